// Round 3
// baseline (362.314 us; speedup 1.0000x reference)
//
#include <hip/hip_runtime.h>
#include <stdint.h>

#define NB 2
#define NSQ 2048
#define NSK 2048
#define ND 1024
#define NH 16
#define NDH 64

typedef unsigned short u16;
typedef unsigned int u32;
typedef __bf16 bf16x8_t __attribute__((ext_vector_type(8)));
typedef float f32x4_t __attribute__((ext_vector_type(4)));

__device__ __forceinline__ float bf2f(u16 u) {
    union { float f; u32 i; } v; v.i = ((u32)u) << 16; return v.f;
}
__device__ __forceinline__ u16 f2bf(float x) {
    union { float f; u32 i; } v; v.f = x;
    u32 r = v.i + 0x7fffu + ((v.i >> 16) & 1u);
    return (u16)(r >> 16);
}

// ---------------------------------------------------------------- dtype detect
// If inputs are float32, the LOW u16 of each float has random exponent bits
// when decoded as bf16 -> values >= 2^14 are near-certain among 512 samples.
// If inputs are bf16 (N(0,1) data), every exponent field <= 0x81 < 0x8D.
__global__ __launch_bounds__(256) void detect_kernel(
    const u16* __restrict__ Q, int* __restrict__ flag)
{
    __shared__ int s;
    if (threadIdx.x == 0) s = 0;
    __syncthreads();
    uint2 x = ((const uint2*)Q)[threadIdx.x];
    u16 a0 = x.x & 0xffff, a1 = x.x >> 16, a2 = x.y & 0xffff, a3 = x.y >> 16;
    bool big = (((a0 >> 7) & 0xff) >= 0x8D) || (((a1 >> 7) & 0xff) >= 0x8D) ||
               (((a2 >> 7) & 0xff) >= 0x8D) || (((a3 >> 7) & 0xff) >= 0x8D);
    if (big) s = 1;
    __syncthreads();
    if (threadIdx.x == 0) *flag = s;   // 1 = f32 inputs, 0 = bf16 inputs
}

// ---------------------------------------------------------------- param canon
// Canonical bf16 copies of all weights/vectors regardless of input dtype.
// blocks [0,4096): W's (1024 elems each); blocks 4096..4105: the 10 vectors.
// canonical vec order: bq,bk,bv,bo, ln_q_g,ln_q_b, ln_kv_g,ln_kv_b, ln_f_g,ln_f_b
__global__ __launch_bounds__(256) void cvt_params_kernel(
    const int* __restrict__ flag,
    const void* __restrict__ Wq, const void* __restrict__ Wk,
    const void* __restrict__ Wv, const void* __restrict__ Wo,
    const void* __restrict__ vbq, const void* __restrict__ vbk,
    const void* __restrict__ vbv, const void* __restrict__ vbo,
    const void* __restrict__ g0, const void* __restrict__ b0,
    const void* __restrict__ g1, const void* __restrict__ b1,
    const void* __restrict__ g2, const void* __restrict__ b2,
    u16* __restrict__ Wc, u16* __restrict__ Vc)
{
    int blk = blockIdx.x;
    const void* src;
    u16* dst;
    size_t srcoff;   // in elements
    if (blk < 4096) {
        int w = blk >> 10;
        src = (w == 0) ? Wq : (w == 1) ? Wk : (w == 2) ? Wv : Wo;
        srcoff = (size_t)(blk & 1023) * 1024;
        dst = Wc + (size_t)w * 1024 * 1024 + srcoff;
    } else {
        int v = blk - 4096;
        src = (v == 0) ? vbq : (v == 1) ? vbk : (v == 2) ? vbv : (v == 3) ? vbo :
              (v == 4) ? g0  : (v == 5) ? b0  : (v == 6) ? g1  : (v == 7) ? b1 :
              (v == 8) ? g2  : b2;
        srcoff = 0;
        dst = Vc + (size_t)v * 1024;
    }
    int t = threadIdx.x;
    u32 lo, hi;
    if (*flag) {
        float4 x = ((const float4*)src)[srcoff / 4 + t];
        lo = (u32)f2bf(x.x) | ((u32)f2bf(x.y) << 16);
        hi = (u32)f2bf(x.z) | ((u32)f2bf(x.w) << 16);
    } else {
        uint2 x = ((const uint2*)src)[srcoff / 4 + t];
        lo = x.x; hi = x.y;
    }
    uint2 o; o.x = lo; o.y = hi;
    ((uint2*)dst)[t] = o;
}

// ---------------------------------------------------------------- LN (inputs)
__global__ __launch_bounds__(256) void ln_in_kernel(
    const int* __restrict__ flag,
    const void* __restrict__ Q, const void* __restrict__ K,
    const u16* __restrict__ Vc,
    u16* __restrict__ Qn, u16* __restrict__ Kn)
{
    int row = blockIdx.x;
    const void* x; const u16 *g, *bb; u16* y;
    size_t roff;
    if (row < NB * NSQ) {
        x = Q; roff = (size_t)row * ND;
        g = Vc + 4 * 1024; bb = Vc + 5 * 1024;
        y = Qn + roff;
    } else {
        int r2 = row - NB * NSQ;
        x = K; roff = (size_t)r2 * ND;
        g = Vc + 6 * 1024; bb = Vc + 7 * 1024;
        y = Kn + roff;
    }
    int t = threadIdx.x;
    float v0, v1, v2, v3;
    if (*flag) {
        float4 xv = ((const float4*)x)[roff / 4 + t];
        v0 = xv.x; v1 = xv.y; v2 = xv.z; v3 = xv.w;
    } else {
        uint2 ux = ((const uint2*)x)[roff / 4 + t];
        v0 = bf2f(ux.x & 0xffff); v1 = bf2f(ux.x >> 16);
        v2 = bf2f(ux.y & 0xffff); v3 = bf2f(ux.y >> 16);
    }
    float s1 = v0 + v1 + v2 + v3;
    float s2 = v0*v0 + v1*v1 + v2*v2 + v3*v3;
#pragma unroll
    for (int off = 32; off >= 1; off >>= 1) {
        s1 += __shfl_xor(s1, off);
        s2 += __shfl_xor(s2, off);
    }
    __shared__ float r1[4], r2[4];
    int wave = t >> 6;
    if ((t & 63) == 0) { r1[wave] = s1; r2[wave] = s2; }
    __syncthreads();
    float t1 = r1[0] + r1[1] + r1[2] + r1[3];
    float t2 = r2[0] + r2[1] + r2[2] + r2[3];
    float mean = t1 * (1.0f / ND);
    float var  = t2 * (1.0f / ND) - mean * mean;
    float rstd = rsqrtf(var + 1e-5f);
    uint2 ug = ((const uint2*)g)[t];
    uint2 ub = ((const uint2*)bb)[t];
    float y0 = (v0 - mean) * rstd * bf2f(ug.x & 0xffff) + bf2f(ub.x & 0xffff);
    float y1 = (v1 - mean) * rstd * bf2f(ug.x >> 16)    + bf2f(ub.x >> 16);
    float y2 = (v2 - mean) * rstd * bf2f(ug.y & 0xffff) + bf2f(ub.y & 0xffff);
    float y3 = (v3 - mean) * rstd * bf2f(ug.y >> 16)    + bf2f(ub.y >> 16);
    uint2 o;
    o.x = (u32)f2bf(y0) | ((u32)f2bf(y1) << 16);
    o.y = (u32)f2bf(y2) | ((u32)f2bf(y3) << 16);
    ((uint2*)y)[t] = o;
}

// ---------------------------------------------------------------- fused 4x GEMM
// z=0: Qn@Wq^T+bq -> Q1 ; z=1: Kn@Wk^T+bk -> K1 ; z=2: Kn@Wv^T+bv -> V1
// z=3: relu(Qn@Wo^T+bo) -> R.  All outputs bf16.  W/bias from canonical copies.
__global__ __launch_bounds__(256) void gemm4_kernel(
    const u16* __restrict__ Qn, const u16* __restrict__ Kn,
    const u16* __restrict__ Wc, const u16* __restrict__ Vc,
    u16* __restrict__ Q1, u16* __restrict__ K1, u16* __restrict__ V1,
    u16* __restrict__ R)
{
    int z = blockIdx.z;
    const u16* X    = (z == 0 || z == 3) ? Qn : Kn;
    const u16* W    = Wc + (size_t)z * 1024 * 1024;
    const u16* bias = Vc + (size_t)z * 1024;

    __shared__ u16 sA[128 * 32];
    __shared__ u16 sB[128 * 32];

    int tid  = threadIdx.x;
    int wave = tid >> 6, lane = tid & 63;
    int wm = wave >> 1, wn = wave & 1;
    int m0 = blockIdx.x * 128;
    int n0 = blockIdx.y * 128;

    int srow = tid >> 2;
    int scol = (tid & 3) * 8;
    const u16* gA = X + (size_t)(m0 + srow) * ND + scol;
    const u16* gB = W + (size_t)(n0 + srow) * ND + scol;

    uint4 ra0 = *(const uint4*)(gA);
    uint4 ra1 = *(const uint4*)(gA + (size_t)64 * ND);
    uint4 rb0 = *(const uint4*)(gB);
    uint4 rb1 = *(const uint4*)(gB + (size_t)64 * ND);

    f32x4_t acc[4][4];
#pragma unroll
    for (int i = 0; i < 4; ++i)
#pragma unroll
        for (int j = 0; j < 4; ++j)
            acc[i][j] = (f32x4_t){0.f, 0.f, 0.f, 0.f};

    for (int kb = 0; kb < ND / 32; ++kb) {
        *(uint4*)(sA + srow * 32 + scol)        = ra0;
        *(uint4*)(sA + (srow + 64) * 32 + scol) = ra1;
        *(uint4*)(sB + srow * 32 + scol)        = rb0;
        *(uint4*)(sB + (srow + 64) * 32 + scol) = rb1;
        __syncthreads();

        if (kb + 1 < ND / 32) {
            int k0 = (kb + 1) * 32;
            ra0 = *(const uint4*)(gA + k0);
            ra1 = *(const uint4*)(gA + (size_t)64 * ND + k0);
            rb0 = *(const uint4*)(gB + k0);
            rb1 = *(const uint4*)(gB + (size_t)64 * ND + k0);
        }

        bf16x8_t af[4], bfr[4];
#pragma unroll
        for (int tm = 0; tm < 4; ++tm) {
            int rr = wm * 64 + tm * 16 + (lane & 15);
            af[tm] = *(const bf16x8_t*)(sA + rr * 32 + (lane >> 4) * 8);
        }
#pragma unroll
        for (int tn = 0; tn < 4; ++tn) {
            int rr = wn * 64 + tn * 16 + (lane & 15);
            bfr[tn] = *(const bf16x8_t*)(sB + rr * 32 + (lane >> 4) * 8);
        }
#pragma unroll
        for (int tm = 0; tm < 4; ++tm)
#pragma unroll
            for (int tn = 0; tn < 4; ++tn)
                acc[tm][tn] = __builtin_amdgcn_mfma_f32_16x16x32_bf16(
                    af[tm], bfr[tn], acc[tm][tn], 0, 0, 0);
        __syncthreads();
    }

    u16* outp = (z == 0) ? Q1 : (z == 1) ? K1 : (z == 2) ? V1 : R;
#pragma unroll
    for (int tm = 0; tm < 4; ++tm) {
#pragma unroll
        for (int tn = 0; tn < 4; ++tn) {
            int n = n0 + wn * 64 + tn * 16 + (lane & 15);
            float bv_ = bf2f(bias[n]);
#pragma unroll
            for (int r = 0; r < 4; ++r) {
                int m = m0 + wm * 64 + tm * 16 + (lane >> 4) * 4 + r;
                float val = acc[tm][tn][r] + bv_;
                if (z == 3) val = fmaxf(val, 0.f);
                outp[(size_t)m * ND + n] = f2bf(val);
            }
        }
    }
}

// ---------------------------------------------------------------- flash attention
// grid (SQ/64, H, B); block 256 (4 waves). Accumulates O1 INTO R (R += O1).
__global__ __launch_bounds__(256) void attn_kernel(
    const u16* __restrict__ Q1, const u16* __restrict__ K1,
    const u16* __restrict__ V1, const int* __restrict__ mask,
    u16* __restrict__ R)
{
    int q0 = blockIdx.x * 64;
    int h  = blockIdx.y;
    int b  = blockIdx.z;

    __shared__ u16 sQ[64 * 64];
    __shared__ u16 sK[64 * 64];
    __shared__ u16 sVt[64 * 64];
    __shared__ u16 sP[64 * 64];
    __shared__ float sS[64 * 64];
    __shared__ float sMask[64];
    __shared__ float sAlpha[64];
    __shared__ float sL[64];

    int tid  = threadIdx.x;
    int wave = tid >> 6, lane = tid & 63;

    {
        int row = tid >> 2, col = (tid & 3) * 16;
        const uint4* g = (const uint4*)(Q1 + (size_t)(b * NSQ + q0 + row) * ND + h * NDH + col);
        uint4 a0 = g[0], a1 = g[1];
        uint4* l = (uint4*)(sQ + row * 64 + col);
        l[0] = a0; l[1] = a1;
    }

    const float NEG = -1e30f;
    float m_run = NEG, l_run = 0.f;

    f32x4_t acc_o[4];
#pragma unroll
    for (int j = 0; j < 4; ++j) acc_o[j] = (f32x4_t){0.f, 0.f, 0.f, 0.f};

    for (int kb = 0; kb < NSK / 64; ++kb) {
        __syncthreads();
        int k0 = kb * 64;
        {
            int row = tid >> 2, col = (tid & 3) * 16;
            const uint4* gk = (const uint4*)(K1 + (size_t)(b * NSK + k0 + row) * ND + h * NDH + col);
            uint4 a0 = gk[0], a1 = gk[1];
            uint4* l = (uint4*)(sK + row * 64 + col);
            l[0] = a0; l[1] = a1;
            const uint4* gv = (const uint4*)(V1 + (size_t)(b * NSK + k0 + row) * ND + h * NDH + col);
            uint4 w0 = gv[0], w1 = gv[1];
            u16 tmp[16];
            *(uint4*)tmp       = w0;
            *((uint4*)tmp + 1) = w1;
#pragma unroll
            for (int j = 0; j < 16; ++j) sVt[(col + j) * 64 + row] = tmp[j];
        }
        if (tid < 64) sMask[tid] = (float)mask[b * NSK + k0 + tid];
        __syncthreads();

        f32x4_t accs[4];
#pragma unroll
        for (int tn = 0; tn < 4; ++tn) accs[tn] = (f32x4_t){0.f, 0.f, 0.f, 0.f};
#pragma unroll
        for (int kk = 0; kk < 2; ++kk) {
            bf16x8_t aq = *(const bf16x8_t*)(sQ + (wave * 16 + (lane & 15)) * 64 + kk * 32 + (lane >> 4) * 8);
#pragma unroll
            for (int tn = 0; tn < 4; ++tn) {
                bf16x8_t bk_ = *(const bf16x8_t*)(sK + (tn * 16 + (lane & 15)) * 64 + kk * 32 + (lane >> 4) * 8);
                accs[tn] = __builtin_amdgcn_mfma_f32_16x16x32_bf16(aq, bk_, accs[tn], 0, 0, 0);
            }
        }
#pragma unroll
        for (int tn = 0; tn < 4; ++tn)
#pragma unroll
            for (int r = 0; r < 4; ++r)
                sS[(wave * 16 + (lane >> 4) * 4 + r) * 64 + tn * 16 + (lane & 15)] =
                    accs[tn][r] * 0.03125f;
        __syncthreads();

        {
            int row = tid >> 2, c0 = (tid & 3) * 16;
            float sv[16];
            float lmax = NEG;
#pragma unroll
            for (int j = 0; j < 16; ++j) {
                float s = sS[row * 64 + c0 + j];
                sv[j] = (sMask[c0 + j] != 0.f) ? s : NEG;
                lmax = fmaxf(lmax, sv[j]);
            }
            lmax = fmaxf(lmax, __shfl_xor(lmax, 1));
            lmax = fmaxf(lmax, __shfl_xor(lmax, 2));
            float m_new = fmaxf(m_run, lmax);
            float alpha = __expf(m_run - m_new);
            float lsum = 0.f;
#pragma unroll
            for (int j = 0; j < 16; ++j) {
                float p = (sv[j] > -1e29f) ? __expf(sv[j] - m_new) : 0.f;
                lsum += p;
                sP[row * 64 + c0 + j] = f2bf(p);
            }
            lsum += __shfl_xor(lsum, 1);
            lsum += __shfl_xor(lsum, 2);
            l_run = l_run * alpha + lsum;
            m_run = m_new;
            if ((tid & 3) == 0) sAlpha[row] = alpha;
        }
        __syncthreads();

        float al[4];
#pragma unroll
        for (int r = 0; r < 4; ++r) al[r] = sAlpha[wave * 16 + (lane >> 4) * 4 + r];
#pragma unroll
        for (int j = 0; j < 4; ++j)
#pragma unroll
            for (int r = 0; r < 4; ++r) acc_o[j][r] *= al[r];
#pragma unroll
        for (int kk = 0; kk < 2; ++kk) {
            bf16x8_t ap = *(const bf16x8_t*)(sP + (wave * 16 + (lane & 15)) * 64 + kk * 32 + (lane >> 4) * 8);
#pragma unroll
            for (int j = 0; j < 4; ++j) {
                bf16x8_t bv_ = *(const bf16x8_t*)(sVt + (j * 16 + (lane & 15)) * 64 + kk * 32 + (lane >> 4) * 8);
                acc_o[j] = __builtin_amdgcn_mfma_f32_16x16x32_bf16(ap, bv_, acc_o[j], 0, 0, 0);
            }
        }
    }

    if ((tid & 3) == 0) sL[tid >> 2] = l_run;
    __syncthreads();
#pragma unroll
    for (int j = 0; j < 4; ++j)
#pragma unroll
        for (int r = 0; r < 4; ++r) {
            int row = wave * 16 + (lane >> 4) * 4 + r;
            float den = sL[row];
            float inv = den > 0.f ? 1.f / den : 0.f;
            int dh = j * 16 + (lane & 15);
            size_t idx = (size_t)(b * NSQ + q0 + row) * ND + h * NDH + dh;
            float o2v = bf2f(R[idx]);                 // O2 from gemm (z=3)
            R[idx] = f2bf(acc_o[j][r] * inv + o2v);   // R = O1 + O2
        }
}

// ---------------------------------------------------------------- final LN
// out = LN(Q + R) with ln_f params; Q load + out store branch on dtype flag.
__global__ __launch_bounds__(256) void ln_out_kernel(
    const int* __restrict__ flag,
    const void* __restrict__ Q, const u16* __restrict__ R,
    const u16* __restrict__ Vc, void* __restrict__ out)
{
    int row = blockIdx.x;
    size_t roff = (size_t)row * ND;
    int t = threadIdx.x;
    int f = *flag;
    float v0, v1, v2, v3;
    uint2 ur = ((const uint2*)(R + roff))[t];
    if (f) {
        float4 xq = ((const float4*)Q)[roff / 4 + t];
        v0 = xq.x; v1 = xq.y; v2 = xq.z; v3 = xq.w;
    } else {
        uint2 uq = ((const uint2*)Q)[roff / 4 + t];
        v0 = bf2f(uq.x & 0xffff); v1 = bf2f(uq.x >> 16);
        v2 = bf2f(uq.y & 0xffff); v3 = bf2f(uq.y >> 16);
    }
    v0 += bf2f(ur.x & 0xffff); v1 += bf2f(ur.x >> 16);
    v2 += bf2f(ur.y & 0xffff); v3 += bf2f(ur.y >> 16);
    float s1 = v0 + v1 + v2 + v3;
    float s2 = v0*v0 + v1*v1 + v2*v2 + v3*v3;
#pragma unroll
    for (int off = 32; off >= 1; off >>= 1) {
        s1 += __shfl_xor(s1, off);
        s2 += __shfl_xor(s2, off);
    }
    __shared__ float r1[4], r2[4];
    int wave = t >> 6;
    if ((t & 63) == 0) { r1[wave] = s1; r2[wave] = s2; }
    __syncthreads();
    float t1 = r1[0] + r1[1] + r1[2] + r1[3];
    float t2 = r2[0] + r2[1] + r2[2] + r2[3];
    float mean = t1 * (1.0f / ND);
    float var  = t2 * (1.0f / ND) - mean * mean;
    float rstd = rsqrtf(var + 1e-5f);
    const u16* g  = Vc + 8 * 1024;
    const u16* bb = Vc + 9 * 1024;
    uint2 ug = ((const uint2*)g)[t];
    uint2 ub = ((const uint2*)bb)[t];
    float y0 = (v0 - mean) * rstd * bf2f(ug.x & 0xffff) + bf2f(ub.x & 0xffff);
    float y1 = (v1 - mean) * rstd * bf2f(ug.x >> 16)    + bf2f(ub.x >> 16);
    float y2 = (v2 - mean) * rstd * bf2f(ug.y & 0xffff) + bf2f(ub.y & 0xffff);
    float y3 = (v3 - mean) * rstd * bf2f(ug.y >> 16)    + bf2f(ub.y >> 16);
    if (f) {
        float4 o; o.x = y0; o.y = y1; o.z = y2; o.w = y3;
        ((float4*)out)[roff / 4 + t] = o;
    } else {
        uint2 o;
        o.x = (u32)f2bf(y0) | ((u32)f2bf(y1) << 16);
        o.y = (u32)f2bf(y2) | ((u32)f2bf(y3) << 16);
        ((uint2*)out)[roff / 4 + t] = o;
    }
}

// ---------------------------------------------------------------- launch
extern "C" void kernel_launch(void* const* d_in, const int* in_sizes, int n_in,
                              void* d_out, int out_size, void* d_ws, size_t ws_size,
                              hipStream_t stream) {
    const void* Q        = d_in[0];
    const void* K        = d_in[1];
    const int* pad_mask  = (const int*)d_in[2];

    const size_t NEL = (size_t)NB * NSQ * ND;   // 4,194,304
    int* flag = (int*)d_ws;
    u16* base = (u16*)d_ws + 128;               // data starts 256 B in
    u16* Qn = base;
    u16* Kn = Qn + NEL;
    u16* Q1 = Kn + NEL;
    u16* K1 = Q1 + NEL;
    u16* V1 = K1 + NEL;
    u16* R  = V1 + NEL;                          // O2 then O1+O2
    u16* Wc = R  + NEL;                          // 4 x 1M canonical weights
    u16* Vc = Wc + (size_t)4 * 1024 * 1024;      // 10 x 1024 canonical vectors

    detect_kernel<<<dim3(1), dim3(256), 0, stream>>>((const u16*)Q, flag);

    cvt_params_kernel<<<dim3(4106), dim3(256), 0, stream>>>(
        flag, d_in[3], d_in[4], d_in[5], d_in[6],
        d_in[7], d_in[8], d_in[9], d_in[10],
        d_in[11], d_in[12], d_in[13], d_in[14], d_in[15], d_in[16],
        Wc, Vc);

    ln_in_kernel<<<dim3(2 * NB * NSQ), dim3(256), 0, stream>>>(
        flag, Q, K, Vc, Qn, Kn);

    gemm4_kernel<<<dim3(32, 8, 4), dim3(256), 0, stream>>>(
        Qn, Kn, Wc, Vc, Q1, K1, V1, R);

    attn_kernel<<<dim3(NSQ / 64, NH, NB), dim3(256), 0, stream>>>(
        Q1, K1, V1, pad_mask, R);

    ln_out_kernel<<<dim3(NB * NSQ), dim3(256), 0, stream>>>(
        flag, Q, R, Vc, d_out);
}

// Round 4
// 287.041 us; speedup vs baseline: 1.2622x; 1.2622x over previous
//
#include <hip/hip_runtime.h>
#include <stdint.h>

#define NB 2
#define NSQ 2048
#define NSK 2048
#define ND 1024
#define NH 16
#define NDH 64

typedef unsigned short u16;
typedef unsigned int u32;
typedef __bf16 bf16x8_t __attribute__((ext_vector_type(8)));
typedef float f32x4_t __attribute__((ext_vector_type(4)));
typedef u32 u32x4_t __attribute__((ext_vector_type(4)));

__device__ __forceinline__ float bf2f(u16 u) {
    union { float f; u32 i; } v; v.i = ((u32)u) << 16; return v.f;
}
__device__ __forceinline__ u16 f2bf(float x) {
    union { float f; u32 i; } v; v.f = x;
    u32 r = v.i + 0x7fffu + ((v.i >> 16) & 1u);
    return (u16)(r >> 16);
}
__device__ __forceinline__ u32 fbits(float x) {
    union { float f; u32 i; } v; v.f = x; return v.i;
}
__device__ __forceinline__ float bitsf(u32 x) {
    union { float f; u32 i; } v; v.i = x; return v.f;
}

// ---------------------------------------------------------------- dtype detect
__global__ __launch_bounds__(256) void detect_kernel(
    const u16* __restrict__ Q, int* __restrict__ flag)
{
    __shared__ int s;
    if (threadIdx.x == 0) s = 0;
    __syncthreads();
    uint2 x = ((const uint2*)Q)[threadIdx.x];
    u16 a0 = x.x & 0xffff, a1 = x.x >> 16, a2 = x.y & 0xffff, a3 = x.y >> 16;
    bool big = (((a0 >> 7) & 0xff) >= 0x8D) || (((a1 >> 7) & 0xff) >= 0x8D) ||
               (((a2 >> 7) & 0xff) >= 0x8D) || (((a3 >> 7) & 0xff) >= 0x8D);
    if (big) s = 1;
    __syncthreads();
    if (threadIdx.x == 0) *flag = s;   // 1 = f32 inputs, 0 = bf16 inputs
}

// ---------------------------------------------------------------- param canon
// canonical vec order: bq,bk,bv,bo, ln_q_g,ln_q_b, ln_kv_g,ln_kv_b, ln_f_g,ln_f_b
__global__ __launch_bounds__(256) void cvt_params_kernel(
    const int* __restrict__ flag,
    const void* __restrict__ Wq, const void* __restrict__ Wk,
    const void* __restrict__ Wv, const void* __restrict__ Wo,
    const void* __restrict__ vbq, const void* __restrict__ vbk,
    const void* __restrict__ vbv, const void* __restrict__ vbo,
    const void* __restrict__ g0, const void* __restrict__ b0,
    const void* __restrict__ g1, const void* __restrict__ b1,
    const void* __restrict__ g2, const void* __restrict__ b2,
    u16* __restrict__ Wc, u16* __restrict__ Vc)
{
    int blk = blockIdx.x;
    const void* src;
    u16* dst;
    size_t srcoff;
    if (blk < 4096) {
        int w = blk >> 10;
        src = (w == 0) ? Wq : (w == 1) ? Wk : (w == 2) ? Wv : Wo;
        srcoff = (size_t)(blk & 1023) * 1024;
        dst = Wc + (size_t)w * 1024 * 1024 + srcoff;
    } else {
        int v = blk - 4096;
        src = (v == 0) ? vbq : (v == 1) ? vbk : (v == 2) ? vbv : (v == 3) ? vbo :
              (v == 4) ? g0  : (v == 5) ? b0  : (v == 6) ? g1  : (v == 7) ? b1 :
              (v == 8) ? g2  : b2;
        srcoff = 0;
        dst = Vc + (size_t)v * 1024;
    }
    int t = threadIdx.x;
    u32 lo, hi;
    if (*flag) {
        float4 x = ((const float4*)src)[srcoff / 4 + t];
        lo = (u32)f2bf(x.x) | ((u32)f2bf(x.y) << 16);
        hi = (u32)f2bf(x.z) | ((u32)f2bf(x.w) << 16);
    } else {
        uint2 x = ((const uint2*)src)[srcoff / 4 + t];
        lo = x.x; hi = x.y;
    }
    uint2 o; o.x = lo; o.y = hi;
    ((uint2*)dst)[t] = o;
}

// ---------------------------------------------------------------- LN (inputs)
__global__ __launch_bounds__(256) void ln_in_kernel(
    const int* __restrict__ flag,
    const void* __restrict__ Q, const void* __restrict__ K,
    const u16* __restrict__ Vc,
    u16* __restrict__ Qn, u16* __restrict__ Kn)
{
    int row = blockIdx.x;
    const void* x; const u16 *g, *bb; u16* y;
    size_t roff;
    if (row < NB * NSQ) {
        x = Q; roff = (size_t)row * ND;
        g = Vc + 4 * 1024; bb = Vc + 5 * 1024;
        y = Qn + roff;
    } else {
        int r2 = row - NB * NSQ;
        x = K; roff = (size_t)r2 * ND;
        g = Vc + 6 * 1024; bb = Vc + 7 * 1024;
        y = Kn + roff;
    }
    int t = threadIdx.x;
    float v0, v1, v2, v3;
    if (*flag) {
        float4 xv = ((const float4*)x)[roff / 4 + t];
        v0 = xv.x; v1 = xv.y; v2 = xv.z; v3 = xv.w;
    } else {
        uint2 ux = ((const uint2*)x)[roff / 4 + t];
        v0 = bf2f(ux.x & 0xffff); v1 = bf2f(ux.x >> 16);
        v2 = bf2f(ux.y & 0xffff); v3 = bf2f(ux.y >> 16);
    }
    float s1 = v0 + v1 + v2 + v3;
    float s2 = v0*v0 + v1*v1 + v2*v2 + v3*v3;
#pragma unroll
    for (int off = 32; off >= 1; off >>= 1) {
        s1 += __shfl_xor(s1, off);
        s2 += __shfl_xor(s2, off);
    }
    __shared__ float r1[4], r2[4];
    int wave = t >> 6;
    if ((t & 63) == 0) { r1[wave] = s1; r2[wave] = s2; }
    __syncthreads();
    float t1 = r1[0] + r1[1] + r1[2] + r1[3];
    float t2 = r2[0] + r2[1] + r2[2] + r2[3];
    float mean = t1 * (1.0f / ND);
    float var  = t2 * (1.0f / ND) - mean * mean;
    float rstd = rsqrtf(var + 1e-5f);
    uint2 ug = ((const uint2*)g)[t];
    uint2 ub = ((const uint2*)bb)[t];
    float y0 = (v0 - mean) * rstd * bf2f(ug.x & 0xffff) + bf2f(ub.x & 0xffff);
    float y1 = (v1 - mean) * rstd * bf2f(ug.x >> 16)    + bf2f(ub.x >> 16);
    float y2 = (v2 - mean) * rstd * bf2f(ug.y & 0xffff) + bf2f(ub.y & 0xffff);
    float y3 = (v3 - mean) * rstd * bf2f(ug.y >> 16)    + bf2f(ub.y >> 16);
    uint2 o;
    o.x = (u32)f2bf(y0) | ((u32)f2bf(y1) << 16);
    o.y = (u32)f2bf(y2) | ((u32)f2bf(y3) << 16);
    ((uint2*)y)[t] = o;
}

// ---------------------------------------------------------------- fused 4x GEMM
// z=0: (Qn@Wq^T+bq)/32 -> Q1 (scale folded for attention)
// z=1: Kn@Wk^T+bk -> K1
// z=2: Kn@Wv^T+bv -> V1t  TRANSPOSED layout [b][h][d][key]
// z=3: relu(Qn@Wo^T+bo) -> R
__global__ __launch_bounds__(256) void gemm4_kernel(
    const u16* __restrict__ Qn, const u16* __restrict__ Kn,
    const u16* __restrict__ Wc, const u16* __restrict__ Vc,
    u16* __restrict__ Q1, u16* __restrict__ K1, u16* __restrict__ V1t,
    u16* __restrict__ R)
{
    int z = blockIdx.z;
    const u16* X    = (z == 0 || z == 3) ? Qn : Kn;
    const u16* W    = Wc + (size_t)z * 1024 * 1024;
    const u16* bias = Vc + (size_t)z * 1024;

    __shared__ u16 sA[128 * 32];
    __shared__ u16 sB[128 * 32];

    int tid  = threadIdx.x;
    int wave = tid >> 6, lane = tid & 63;
    int wm = wave >> 1, wn = wave & 1;
    int m0 = blockIdx.x * 128;
    int n0 = blockIdx.y * 128;

    int srow = tid >> 2;
    int scol = (tid & 3) * 8;
    const u16* gA = X + (size_t)(m0 + srow) * ND + scol;
    const u16* gB = W + (size_t)(n0 + srow) * ND + scol;

    uint4 ra0 = *(const uint4*)(gA);
    uint4 ra1 = *(const uint4*)(gA + (size_t)64 * ND);
    uint4 rb0 = *(const uint4*)(gB);
    uint4 rb1 = *(const uint4*)(gB + (size_t)64 * ND);

    f32x4_t acc[4][4];
#pragma unroll
    for (int i = 0; i < 4; ++i)
#pragma unroll
        for (int j = 0; j < 4; ++j)
            acc[i][j] = (f32x4_t){0.f, 0.f, 0.f, 0.f};

    for (int kb = 0; kb < ND / 32; ++kb) {
        *(uint4*)(sA + srow * 32 + scol)        = ra0;
        *(uint4*)(sA + (srow + 64) * 32 + scol) = ra1;
        *(uint4*)(sB + srow * 32 + scol)        = rb0;
        *(uint4*)(sB + (srow + 64) * 32 + scol) = rb1;
        __syncthreads();

        if (kb + 1 < ND / 32) {
            int k0 = (kb + 1) * 32;
            ra0 = *(const uint4*)(gA + k0);
            ra1 = *(const uint4*)(gA + (size_t)64 * ND + k0);
            rb0 = *(const uint4*)(gB + k0);
            rb1 = *(const uint4*)(gB + (size_t)64 * ND + k0);
        }

        bf16x8_t af[4], bfr[4];
#pragma unroll
        for (int tm = 0; tm < 4; ++tm) {
            int rr = wm * 64 + tm * 16 + (lane & 15);
            af[tm] = *(const bf16x8_t*)(sA + rr * 32 + (lane >> 4) * 8);
        }
#pragma unroll
        for (int tn = 0; tn < 4; ++tn) {
            int rr = wn * 64 + tn * 16 + (lane & 15);
            bfr[tn] = *(const bf16x8_t*)(sB + rr * 32 + (lane >> 4) * 8);
        }
#pragma unroll
        for (int tm = 0; tm < 4; ++tm)
#pragma unroll
            for (int tn = 0; tn < 4; ++tn)
                acc[tm][tn] = __builtin_amdgcn_mfma_f32_16x16x32_bf16(
                    af[tm], bfr[tn], acc[tm][tn], 0, 0, 0);
        __syncthreads();
    }

#pragma unroll
    for (int tm = 0; tm < 4; ++tm) {
#pragma unroll
        for (int tn = 0; tn < 4; ++tn) {
            int n = n0 + wn * 64 + tn * 16 + (lane & 15);
            float bv_ = bf2f(bias[n]);
#pragma unroll
            for (int r = 0; r < 4; ++r) {
                int m = m0 + wm * 64 + tm * 16 + (lane >> 4) * 4 + r;
                float val = acc[tm][tn][r] + bv_;
                if (z == 0) {
                    Q1[(size_t)m * ND + n] = f2bf(val * 0.03125f);  // fold 1/sqrt(D)
                } else if (z == 1) {
                    K1[(size_t)m * ND + n] = f2bf(val);
                } else if (z == 2) {
                    int bb_ = m >> 11, key = m & 2047, hh = n >> 6, dd = n & 63;
                    V1t[((size_t)(bb_ * 16 + hh) * 64 + dd) * 2048 + key] = f2bf(val);
                } else {
                    R[(size_t)m * ND + n] = f2bf(fmaxf(val, 0.f));
                }
            }
        }
    }
}

// ---------------------------------------------------------------- flash attention
// S^T = K.Q^T formulation: softmax state is per-lane scalar (q = lane&15).
// grid (SQ/64, H, B); block 256 (4 waves), wave w owns q-tile w*16..w*16+15.
// Accumulates O1 into R (R = O1 + O2).
__global__ __launch_bounds__(256, 4) void attn_kernel(
    const u16* __restrict__ Q1, const u16* __restrict__ K1,
    const u16* __restrict__ V1t, const int* __restrict__ mask,
    u16* __restrict__ R)
{
    int q0 = blockIdx.x * 64;
    int h  = blockIdx.y;
    int b  = blockIdx.z;

    __shared__ u16 sK[64 * 72];     // [key][dh], stride 72 (pad kills conflicts)
    __shared__ u16 sVt[64 * 72];    // [d][key], stride 72
    __shared__ float sM[2048];      // mask as float, whole row of keys

    int tid  = threadIdx.x;
    int wave = tid >> 6, lane = tid & 63;
    int quad = lane >> 4, l4 = lane & 15;

    // preload mask as float (once per block)
    for (int i = tid; i < 2048 / 4; i += 256) {
        int4 mi = ((const int4*)(mask + b * NSK))[i];
        float4 mf; mf.x = (float)mi.x; mf.y = (float)mi.y;
        mf.z = (float)mi.z; mf.w = (float)mi.w;
        ((float4*)sM)[i] = mf;
    }

    // Q B-operand fragments, straight from global into registers (once)
    bf16x8_t qf[2];
    {
        const u16* qp = Q1 + (size_t)(b * NSQ + q0 + wave * 16 + l4) * ND + h * NDH;
        qf[0] = *(const bf16x8_t*)(qp + quad * 8);
        qf[1] = *(const bf16x8_t*)(qp + 32 + quad * 8);
    }

    float m_run = -1e30f, l_run = 0.f;   // per-lane: q = l4 of this wave's tile
    f32x4_t acc_o[4];                    // O^T C-layout: d = T*16+quad*4+r, col q=l4
#pragma unroll
    for (int T = 0; T < 4; ++T) acc_o[T] = (f32x4_t){0.f, 0.f, 0.f, 0.f};

    int srcA = ((lane >> 4) & 1) * 32 + l4;  // P^T shuffle sources
    int srcB = srcA + 16;
    bool hi = lane >= 32;

    for (int kb = 0; kb < NSK / 64; ++kb) {
        __syncthreads();
        // stage K tile [key][dh] and V^T tile [d][key] (both coalesced b128)
        {
            int row = tid >> 3, seg = tid & 7;
            const u16* gk = K1 + (size_t)(b * NSK + kb * 64 + row) * ND + h * NDH + seg * 8;
            *(uint4*)(sK + row * 72 + seg * 8)        = *(const uint4*)gk;
            *(uint4*)(sK + (row + 32) * 72 + seg * 8) = *(const uint4*)(gk + (size_t)32 * ND);
            const u16* gv = V1t + ((size_t)(b * 16 + h) * 64 + row) * 2048 + kb * 64 + seg * 8;
            *(uint4*)(sVt + row * 72 + seg * 8)        = *(const uint4*)gv;
            *(uint4*)(sVt + (row + 32) * 72 + seg * 8) = *(const uint4*)(gv + 32 * 2048);
        }
        __syncthreads();

        // S^T = K @ Q^T : accs[tm] C-layout: key = tm*16+quad*4+r, col q = l4
        f32x4_t accs[4];
#pragma unroll
        for (int tm = 0; tm < 4; ++tm) accs[tm] = (f32x4_t){0.f, 0.f, 0.f, 0.f};
#pragma unroll
        for (int kk = 0; kk < 2; ++kk)
#pragma unroll
            for (int tm = 0; tm < 4; ++tm) {
                bf16x8_t kf = *(const bf16x8_t*)(sK + (tm * 16 + l4) * 72 + kk * 32 + quad * 8);
                accs[tm] = __builtin_amdgcn_mfma_f32_16x16x32_bf16(kf, qf[kk], accs[tm], 0, 0, 0);
            }

        // mask values for this lane's 16 keys (broadcast f32x4 reads)
        f32x4_t mv[4];
#pragma unroll
        for (int tm = 0; tm < 4; ++tm)
            mv[tm] = *(const f32x4_t*)(sM + kb * 64 + tm * 16 + quad * 4);

        // in-register online softmax (per-lane scalar state)
        float mloc = -1e30f;
#pragma unroll
        for (int tm = 0; tm < 4; ++tm)
#pragma unroll
            for (int r = 0; r < 4; ++r) mloc = fmaxf(mloc, accs[tm][r]);
        mloc = fmaxf(mloc, __shfl_xor(mloc, 16));
        mloc = fmaxf(mloc, __shfl_xor(mloc, 32));
        float m_new = fmaxf(m_run, mloc);
        float alpha = __expf(m_run - m_new);
        float lsum = 0.f;
        u32 pk[4][2];   // packed bf16 pairs of P^T (truncation; l uses same values)
#pragma unroll
        for (int tm = 0; tm < 4; ++tm) {
            u32 pb[4];
#pragma unroll
            for (int r = 0; r < 4; ++r) {
                float p = __expf(accs[tm][r] - m_new) * mv[tm][r];
                u32 tb = fbits(p) & 0xffff0000u;
                lsum += bitsf(tb);
                pb[r] = tb;
            }
            pk[tm][0] = (pb[0] >> 16) | pb[1];
            pk[tm][1] = (pb[2] >> 16) | pb[3];
        }
        lsum += __shfl_xor(lsum, 16);
        lsum += __shfl_xor(lsum, 32);
        l_run = l_run * alpha + lsum;
        m_run = m_new;

        // rescale O accumulator (scalar alpha), then O^T += V^T @ P^T
#pragma unroll
        for (int T = 0; T < 4; ++T)
#pragma unroll
            for (int r = 0; r < 4; ++r) acc_o[T][r] *= alpha;

#pragma unroll
        for (int kk = 0; kk < 2; ++kk) {
            // build P^T B-fragment via cross-lane shuffles (no LDS round-trip)
            u32 a0 = __shfl((int)pk[kk * 2][0], srcA), a1 = __shfl((int)pk[kk * 2][1], srcA);
            u32 b0 = __shfl((int)pk[kk * 2 + 1][0], srcA), b1 = __shfl((int)pk[kk * 2 + 1][1], srcA);
            u32 c0 = __shfl((int)pk[kk * 2][0], srcB), c1 = __shfl((int)pk[kk * 2][1], srcB);
            u32 d0 = __shfl((int)pk[kk * 2 + 1][0], srcB), d1 = __shfl((int)pk[kk * 2 + 1][1], srcB);
            u32x4_t pr;
            pr.x = hi ? b0 : a0;
            pr.y = hi ? b1 : a1;
            pr.z = hi ? d0 : c0;
            pr.w = hi ? d1 : c1;
            bf16x8_t pf = __builtin_bit_cast(bf16x8_t, pr);
#pragma unroll
            for (int T = 0; T < 4; ++T) {
                bf16x8_t vf = *(const bf16x8_t*)(sVt + (T * 16 + l4) * 72 + kk * 32 + quad * 8);
                acc_o[T] = __builtin_amdgcn_mfma_f32_16x16x32_bf16(vf, pf, acc_o[T], 0, 0, 0);
            }
        }
    }

    // epilogue: O[q][d] = acc_o / l ; R += O1 (uint2 RMW, coalesced)
    float inv = l_run > 0.f ? 1.f / l_run : 0.f;
    u16* rp = R + (size_t)(b * NSQ + q0 + wave * 16 + l4) * ND + h * NDH;
#pragma unroll
    for (int T = 0; T < 4; ++T) {
        u16* p = rp + T * 16 + quad * 4;
        uint2 o2 = *(const uint2*)p;
        float e0 = acc_o[T][0] * inv + bf2f(o2.x & 0xffff);
        float e1 = acc_o[T][1] * inv + bf2f(o2.x >> 16);
        float e2 = acc_o[T][2] * inv + bf2f(o2.y & 0xffff);
        float e3 = acc_o[T][3] * inv + bf2f(o2.y >> 16);
        uint2 on;
        on.x = (u32)f2bf(e0) | ((u32)f2bf(e1) << 16);
        on.y = (u32)f2bf(e2) | ((u32)f2bf(e3) << 16);
        *(uint2*)p = on;
    }
}

// ---------------------------------------------------------------- final LN
__global__ __launch_bounds__(256) void ln_out_kernel(
    const int* __restrict__ flag,
    const void* __restrict__ Q, const u16* __restrict__ R,
    const u16* __restrict__ Vc, void* __restrict__ out)
{
    int row = blockIdx.x;
    size_t roff = (size_t)row * ND;
    int t = threadIdx.x;
    int f = *flag;
    float v0, v1, v2, v3;
    uint2 ur = ((const uint2*)(R + roff))[t];
    if (f) {
        float4 xq = ((const float4*)Q)[roff / 4 + t];
        v0 = xq.x; v1 = xq.y; v2 = xq.z; v3 = xq.w;
    } else {
        uint2 uq = ((const uint2*)Q)[roff / 4 + t];
        v0 = bf2f(uq.x & 0xffff); v1 = bf2f(uq.x >> 16);
        v2 = bf2f(uq.y & 0xffff); v3 = bf2f(uq.y >> 16);
    }
    v0 += bf2f(ur.x & 0xffff); v1 += bf2f(ur.x >> 16);
    v2 += bf2f(ur.y & 0xffff); v3 += bf2f(ur.y >> 16);
    float s1 = v0 + v1 + v2 + v3;
    float s2 = v0*v0 + v1*v1 + v2*v2 + v3*v3;
#pragma unroll
    for (int off = 32; off >= 1; off >>= 1) {
        s1 += __shfl_xor(s1, off);
        s2 += __shfl_xor(s2, off);
    }
    __shared__ float r1[4], r2[4];
    int wave = t >> 6;
    if ((t & 63) == 0) { r1[wave] = s1; r2[wave] = s2; }
    __syncthreads();
    float t1 = r1[0] + r1[1] + r1[2] + r1[3];
    float t2 = r2[0] + r2[1] + r2[2] + r2[3];
    float mean = t1 * (1.0f / ND);
    float var  = t2 * (1.0f / ND) - mean * mean;
    float rstd = rsqrtf(var + 1e-5f);
    const u16* g  = Vc + 8 * 1024;
    const u16* bb = Vc + 9 * 1024;
    uint2 ug = ((const uint2*)g)[t];
    uint2 ub = ((const uint2*)bb)[t];
    float y0 = (v0 - mean) * rstd * bf2f(ug.x & 0xffff) + bf2f(ub.x & 0xffff);
    float y1 = (v1 - mean) * rstd * bf2f(ug.x >> 16)    + bf2f(ub.x >> 16);
    float y2 = (v2 - mean) * rstd * bf2f(ug.y & 0xffff) + bf2f(ub.y & 0xffff);
    float y3 = (v3 - mean) * rstd * bf2f(ug.y >> 16)    + bf2f(ub.y >> 16);
    if (f) {
        float4 o; o.x = y0; o.y = y1; o.z = y2; o.w = y3;
        ((float4*)out)[roff / 4 + t] = o;
    } else {
        uint2 o;
        o.x = (u32)f2bf(y0) | ((u32)f2bf(y1) << 16);
        o.y = (u32)f2bf(y2) | ((u32)f2bf(y3) << 16);
        ((uint2*)out)[roff / 4 + t] = o;
    }
}

// ---------------------------------------------------------------- launch
extern "C" void kernel_launch(void* const* d_in, const int* in_sizes, int n_in,
                              void* d_out, int out_size, void* d_ws, size_t ws_size,
                              hipStream_t stream) {
    const void* Q        = d_in[0];
    const void* K        = d_in[1];
    const int* pad_mask  = (const int*)d_in[2];

    const size_t NEL = (size_t)NB * NSQ * ND;   // 4,194,304
    int* flag = (int*)d_ws;
    u16* base = (u16*)d_ws + 128;
    u16* Qn  = base;
    u16* Kn  = Qn + NEL;
    u16* Q1  = Kn + NEL;
    u16* K1  = Q1 + NEL;
    u16* V1t = K1 + NEL;                         // transposed [b][h][d][key]
    u16* R   = V1t + NEL;                        // O2 then O1+O2
    u16* Wc  = R + NEL;                          // 4 x 1M canonical weights
    u16* Vc  = Wc + (size_t)4 * 1024 * 1024;     // 10 x 1024 canonical vectors

    detect_kernel<<<dim3(1), dim3(256), 0, stream>>>((const u16*)Q, flag);

    cvt_params_kernel<<<dim3(4106), dim3(256), 0, stream>>>(
        flag, d_in[3], d_in[4], d_in[5], d_in[6],
        d_in[7], d_in[8], d_in[9], d_in[10],
        d_in[11], d_in[12], d_in[13], d_in[14], d_in[15], d_in[16],
        Wc, Vc);

    ln_in_kernel<<<dim3(2 * NB * NSQ), dim3(256), 0, stream>>>(
        flag, Q, K, Vc, Qn, Kn);

    gemm4_kernel<<<dim3(32, 8, 4), dim3(256), 0, stream>>>(
        Qn, Kn, Wc, Vc, Q1, K1, V1t, R);

    attn_kernel<<<dim3(NSQ / 64, NH, NB), dim3(256), 0, stream>>>(
        Q1, K1, V1t, pad_mask, R);

    ln_out_kernel<<<dim3(NB * NSQ), dim3(256), 0, stream>>>(
        flag, Q, R, Vc, d_out);
}